// Round 1
// baseline (780.881 us; speedup 1.0000x reference)
//
#include <hip/hip_runtime.h>

typedef _Float16 half8_t __attribute__((ext_vector_type(8)));
typedef _Float16 half4_t __attribute__((ext_vector_type(4)));
typedef float floatx4 __attribute__((ext_vector_type(4)));

// async global->LDS, 16B per lane. lds ptr must be wave-uniform; HW writes
// lane L's data at ldsbase + L*16.
__device__ inline void gload16(const void* g, void* l) {
  __builtin_amdgcn_global_load_lds(
      (const __attribute__((address_space(1))) unsigned int*)g,
      (__attribute__((address_space(3))) unsigned int*)l, 16, 0, 0);
}

// Read an MFMA A/B fragment (8 halves, k = quad*8..quad*8+7) from LDS stored
// in chunk order [kchunk][row][16B]. For fp32 tiles: chunk = 4 floats, need 2.
template <typename T>
__device__ inline half8_t read_frag(const char* sbase, int row, int quad) {
  if constexpr (sizeof(T) == 4) {
    floatx4 f0 = *(const floatx4*)(sbase + (((quad * 2) * 128 + row) << 4));
    floatx4 f1 = *(const floatx4*)(sbase + (((quad * 2 + 1) * 128 + row) << 4));
    half8_t h;
    h[0] = (_Float16)f0[0]; h[1] = (_Float16)f0[1];
    h[2] = (_Float16)f0[2]; h[3] = (_Float16)f0[3];
    h[4] = (_Float16)f1[0]; h[5] = (_Float16)f1[1];
    h[6] = (_Float16)f1[2]; h[7] = (_Float16)f1[3];
    return h;
  } else {
    return *(const half8_t*)(sbase + ((quad * 128 + row) << 4));
  }
}

// C[m,n] = sum_h A[m,h]*B[n,h] (+bias). Both operands K-contiguous (BT form).
// BIAS: 0 none, 1 per-col(n), 2 per-row(m). KDIM fixed 1024.
constexpr int BM = 128, BN = 128, BK = 32, KDIM = 1024;

template <typename AT, typename BT, typename OT, int BIAS>
__global__ __launch_bounds__(256) void gemm_bt(
    const AT* __restrict__ A, long As, int lda,
    const BT* __restrict__ B, long Bs, int ldb,
    OT* __restrict__ C, long Cs, int ldc,
    const float* __restrict__ bias) {
  constexpr int ACH = sizeof(AT) == 4 ? 8 : 4;  // 16B chunks per BK in A
  constexpr int BCH = sizeof(BT) == 4 ? 8 : 4;
  constexpr int ABYTES = ACH * 128 * 16;
  constexpr int BBYTES = BCH * 128 * 16;
  __shared__ char smem[ABYTES + BBYTES];
  char* sA = smem;
  char* sB = smem + ABYTES;

  const int tid = threadIdx.x;
  const int lane = tid & 63;
  const int wid = tid >> 6;
  const int wm = wid >> 1, wn = wid & 1;
  const int quad = lane >> 4;
  const int mrow = lane & 15;
  const long m0 = (long)blockIdx.y * BM;
  const long n0 = (long)blockIdx.x * BN;
  A += (long)blockIdx.z * As;
  B += (long)blockIdx.z * Bs;
  C += (long)blockIdx.z * Cs;

  floatx4 acc[4][4] = {};

  constexpr int AV = 16 / sizeof(AT);  // elements per 16B chunk
  constexpr int BV = 16 / sizeof(BT);

  for (int k0 = 0; k0 < KDIM; k0 += BK) {
    // ---- stage A: ACH*128 chunks, ACH/2 instructions per wave ----
#pragma unroll
    for (int i = 0; i < ACH / 2; ++i) {
      int lin = (wid * (ACH / 2) + i) * 64 + lane;
      int m = lin & 127;
      int kb = lin >> 7;
      const AT* gp = A + (m0 + m) * (long)lda + k0 + kb * AV;
      char* lp = sA + (long)((wid * (ACH / 2) + i) * 64) * 16;
      gload16(gp, lp);
    }
    // ---- stage B ----
#pragma unroll
    for (int i = 0; i < BCH / 2; ++i) {
      int lin = (wid * (BCH / 2) + i) * 64 + lane;
      int m = lin & 127;
      int kb = lin >> 7;
      const BT* gp = B + (n0 + m) * (long)ldb + k0 + kb * BV;
      char* lp = sB + (long)((wid * (BCH / 2) + i) * 64) * 16;
      gload16(gp, lp);
    }
    __syncthreads();  // compiler drains vmcnt before s_barrier

    half8_t af[4], bf[4];
#pragma unroll
    for (int i = 0; i < 4; ++i)
      af[i] = read_frag<AT>(sA, wm * 64 + i * 16 + mrow, quad);
#pragma unroll
    for (int j = 0; j < 4; ++j)
      bf[j] = read_frag<BT>(sB, wn * 64 + j * 16 + mrow, quad);

#pragma unroll
    for (int i = 0; i < 4; ++i)
#pragma unroll
      for (int j = 0; j < 4; ++j)
        acc[i][j] = __builtin_amdgcn_mfma_f32_16x16x32_f16(af[i], bf[j],
                                                           acc[i][j], 0, 0, 0);
    __syncthreads();
  }

  // epilogue: C/D layout col = lane&15, row = quad*4 + r
#pragma unroll
  for (int i = 0; i < 4; ++i) {
    int rbase = wm * 64 + i * 16 + quad * 4;
#pragma unroll
    for (int j = 0; j < 4; ++j) {
      int cc = (int)n0 + wn * 64 + j * 16 + mrow;
#pragma unroll
      for (int r = 0; r < 4; ++r) {
        long row = m0 + rbase + r;
        float v = acc[i][j][r];
        if constexpr (BIAS == 1) v += bias[cc];
        if constexpr (BIAS == 2) v += bias[(int)row];
        C[row * (long)ldc + cc] = (OT)v;
      }
    }
  }
}

__global__ __launch_bounds__(256) void convert_w(const float* __restrict__ Wq,
                                                 const float* __restrict__ Wk,
                                                 const float* __restrict__ Wv,
                                                 _Float16* __restrict__ out) {
  int i = blockIdx.x * 256 + threadIdx.x;  // one float4 chunk each; 786432 total
  int t = i >> 18;                         // / 262144 chunks per tensor
  int j = i & 262143;
  const float* src = (t == 0) ? Wq : (t == 1) ? Wk : Wv;
  floatx4 v = ((const floatx4*)src)[j];
  half4_t h = {(_Float16)v[0], (_Float16)v[1], (_Float16)v[2], (_Float16)v[3]};
  ((half4_t*)out)[i] = h;
}

// Row softmax over 1024 fp32; writes fp16 P in-place over the row's storage
// (row r fp16 occupies bytes [r*4096, r*4096+2048) -> no cross-row aliasing).
__global__ __launch_bounds__(256) void softmax_rows(float* __restrict__ S) {
  long row = blockIdx.x;
  float* Sr = S + row * 1024;
  int tid = threadIdx.x, lane = tid & 63, wid = tid >> 6;
  floatx4 x = ((const floatx4*)Sr)[tid];
  float mx = fmaxf(fmaxf(x[0], x[1]), fmaxf(x[2], x[3]));
#pragma unroll
  for (int off = 32; off > 0; off >>= 1) mx = fmaxf(mx, __shfl_xor(mx, off));
  __shared__ float redm[4];
  if (lane == 0) redm[wid] = mx;
  __syncthreads();
  mx = fmaxf(fmaxf(redm[0], redm[1]), fmaxf(redm[2], redm[3]));
  float e0 = __expf(x[0] - mx), e1 = __expf(x[1] - mx);
  float e2 = __expf(x[2] - mx), e3 = __expf(x[3] - mx);
  float s = e0 + e1 + e2 + e3;
#pragma unroll
  for (int off = 32; off > 0; off >>= 1) s += __shfl_xor(s, off);
  __shared__ float reds[4];
  if (lane == 0) reds[wid] = s;
  __syncthreads();
  s = reds[0] + reds[1] + reds[2] + reds[3];
  float inv = 1.0f / s;
  half4_t h = {(_Float16)(e0 * inv), (_Float16)(e1 * inv),
               (_Float16)(e2 * inv), (_Float16)(e3 * inv)};
  ((half4_t*)Sr)[tid] = h;  // byte offset tid*8, all reads done pre-barrier
}

extern "C" void kernel_launch(void* const* d_in, const int* in_sizes, int n_in,
                              void* d_out, int out_size, void* d_ws,
                              size_t ws_size, hipStream_t stream) {
  (void)in_sizes; (void)n_in; (void)out_size; (void)ws_size;
  const float* meme  = (const float*)d_in[0];
  const float* text  = (const float*)d_in[1];
  const float* emoji = (const float*)d_in[2];
  const float* Wq = (const float*)d_in[3];
  const float* bq = (const float*)d_in[4];
  const float* Wk = (const float*)d_in[5];
  const float* bk = (const float*)d_in[6];
  const float* Wv = (const float*)d_in[7];
  const float* bv = (const float*)d_in[8];

  const long MB = 1024 * 1024;
  char* ws = (char*)d_ws;
  _Float16* hWq = (_Float16*)ws;            // 2MB
  _Float16* hWk = hWq + MB;                 // 2MB
  _Float16* hWv = hWk + MB;                 // 2MB
  _Float16* Qh = (_Float16*)(ws + 6 * MB);  // 32MB  [16384,1024] fp16
  _Float16* Kh = (_Float16*)(ws + 38 * MB); // 32MB
  _Float16* Vt = (_Float16*)(ws + 70 * MB); // 32MB  [1024, 16384] fp16 (V^T)
  float* S = (float*)(ws + 102 * MB);       // 64MB  [16,1024,1024] fp32

  dim3 blk(256);
  convert_w<<<3072, blk, 0, stream>>>(Wq, Wk, Wv, hWq);

  // Q = meme @ Wq^T + bq  -> fp16 [16384,1024]
  gemm_bt<float, _Float16, _Float16, 1><<<dim3(8, 128, 1), blk, 0, stream>>>(
      meme, 0, 1024, hWq, 0, 1024, Qh, 0, 1024, bq);
  // K = text @ Wk^T + bk
  gemm_bt<float, _Float16, _Float16, 1><<<dim3(8, 128, 1), blk, 0, stream>>>(
      text, 0, 1024, hWk, 0, 1024, Kh, 0, 1024, bk);
  // Vt[a, b*L+l] = sum_h Wv[a,h]*emoji[b,l,h] + bv[a]  (V transposed)
  gemm_bt<_Float16, float, _Float16, 2><<<dim3(128, 8, 1), blk, 0, stream>>>(
      hWv, 0, 1024, emoji, 0, 1024, Vt, 0, 16384, bv);
  // S[b] = Q[b] @ K[b]^T  -> fp32
  gemm_bt<_Float16, _Float16, float, 0><<<dim3(8, 8, 16), blk, 0, stream>>>(
      Qh, 1048576, 1024, Kh, 1048576, 1024, S, 1048576, 1024, nullptr);
  // softmax rows, P fp16 in-place (lda becomes 2048 halves)
  softmax_rows<<<16384, blk, 0, stream>>>(S);
  // O[b] = P[b] @ V[b]  via Vt: C[q,a] = sum_k P[q,k] * Vt[a, b*1024+k]
  gemm_bt<_Float16, _Float16, float, 0><<<dim3(8, 8, 16), blk, 0, stream>>>(
      (const _Float16*)S, 2097152, 2048, Vt, 1024, 16384, (float*)d_out,
      1048576, 1024, nullptr);
}

// Round 2
// 667.882 us; speedup vs baseline: 1.1692x; 1.1692x over previous
//
#include <hip/hip_runtime.h>

typedef _Float16 half8_t __attribute__((ext_vector_type(8)));
typedef _Float16 half4_t __attribute__((ext_vector_type(4)));
typedef float floatx4 __attribute__((ext_vector_type(4)));

// async global->LDS, 16B per lane. lds ptr must be wave-uniform; HW writes
// lane L's data at ldsbase + L*16.
__device__ inline void gload16(const void* g, void* l) {
  __builtin_amdgcn_global_load_lds(
      (const __attribute__((address_space(1))) unsigned int*)g,
      (__attribute__((address_space(3))) unsigned int*)l, 16, 0, 0);
}

// MFMA A/B fragment (8 halves, k = quad*8..) from LDS in chunk order
// [kchunk][row][16B].
__device__ inline half8_t read_frag(const char* sbase, int row, int quad) {
  return *(const half8_t*)(sbase + ((quad * 128 + row) << 4));
}

// C[m,n] = sum_h A[m,h]*B[n,h] (+bias). Both operands fp16, K-contiguous.
// BIAS: 0 none, 1 per-col(n), 2 per-row(m). KDIM fixed 1024.
constexpr int BM = 128, BN = 128, BK = 32, KDIM = 1024;

template <typename OT, int BIAS>
__global__ __launch_bounds__(256) void gemm_bt(
    const _Float16* __restrict__ A, long As, int lda,
    const _Float16* __restrict__ B, long Bs, int ldb,
    OT* __restrict__ C, long Cs, int ldc,
    const float* __restrict__ bias) {
  // fp16: 4 16B-chunks per row per BK; 128 rows -> 8 KB per operand tile
  __shared__ char smem[2 * 4 * 128 * 16];
  char* sA = smem;
  char* sB = smem + 4 * 128 * 16;

  const int tid = threadIdx.x;
  const int lane = tid & 63;
  const int wid = tid >> 6;
  const int wm = wid >> 1, wn = wid & 1;
  const int quad = lane >> 4;
  const int mrow = lane & 15;
  const long m0 = (long)blockIdx.y * BM;
  const long n0 = (long)blockIdx.x * BN;
  A += (long)blockIdx.z * As;
  B += (long)blockIdx.z * Bs;
  C += (long)blockIdx.z * Cs;

  floatx4 acc[4][4] = {};

  for (int k0 = 0; k0 < KDIM; k0 += BK) {
    // stage A: 4*128 chunks = 512; 2 gload16 per wave
#pragma unroll
    for (int i = 0; i < 2; ++i) {
      int lin = (wid * 2 + i) * 64 + lane;
      int m = lin & 127;
      int kb = lin >> 7;
      gload16(A + (m0 + m) * (long)lda + k0 + kb * 8,
              sA + (long)((wid * 2 + i) * 64) * 16);
    }
#pragma unroll
    for (int i = 0; i < 2; ++i) {
      int lin = (wid * 2 + i) * 64 + lane;
      int m = lin & 127;
      int kb = lin >> 7;
      gload16(B + (n0 + m) * (long)ldb + k0 + kb * 8,
              sB + (long)((wid * 2 + i) * 64) * 16);
    }
    __syncthreads();  // drains vmcnt before s_barrier

    half8_t af[4], bf[4];
#pragma unroll
    for (int i = 0; i < 4; ++i)
      af[i] = read_frag(sA, wm * 64 + i * 16 + mrow, quad);
#pragma unroll
    for (int j = 0; j < 4; ++j)
      bf[j] = read_frag(sB, wn * 64 + j * 16 + mrow, quad);

#pragma unroll
    for (int i = 0; i < 4; ++i)
#pragma unroll
      for (int j = 0; j < 4; ++j)
        acc[i][j] = __builtin_amdgcn_mfma_f32_16x16x32_f16(af[i], bf[j],
                                                           acc[i][j], 0, 0, 0);
    __syncthreads();
  }

  // epilogue: C/D layout col = lane&15, row = quad*4 + r
#pragma unroll
  for (int i = 0; i < 4; ++i) {
    int rbase = wm * 64 + i * 16 + quad * 4;
#pragma unroll
    for (int j = 0; j < 4; ++j) {
      int cc = (int)n0 + wn * 64 + j * 16 + mrow;
#pragma unroll
      for (int r = 0; r < 4; ++r) {
        long row = m0 + rbase + r;
        float v = acc[i][j][r];
        if constexpr (BIAS == 1) v += bias[cc];
        if constexpr (BIAS == 2) v += bias[(int)row];
        C[row * (long)ldc + cc] = (OT)v;
      }
    }
  }
}

// fp32 -> fp16, one float4 chunk per thread, 3 tensors of 16M floats each.
__global__ __launch_bounds__(256) void convert_x(const float* __restrict__ x0,
                                                 const float* __restrict__ x1,
                                                 const float* __restrict__ x2,
                                                 _Float16* __restrict__ out) {
  int i = blockIdx.x * 256 + threadIdx.x;  // 12582912 chunks total
  int t = i >> 22;                         // 4194304 chunks per tensor
  int j = i & 4194303;
  const float* src = (t == 0) ? x0 : (t == 1) ? x1 : x2;
  floatx4 v = ((const floatx4*)src)[j];
  half4_t h = {(_Float16)v[0], (_Float16)v[1], (_Float16)v[2], (_Float16)v[3]};
  ((half4_t*)out)[i] = h;
}

__global__ __launch_bounds__(256) void convert_w(const float* __restrict__ Wq,
                                                 const float* __restrict__ Wk,
                                                 const float* __restrict__ Wv,
                                                 _Float16* __restrict__ out) {
  int i = blockIdx.x * 256 + threadIdx.x;  // 786432 chunks total
  int t = i >> 18;                         // 262144 chunks per tensor
  int j = i & 262143;
  const float* src = (t == 0) ? Wq : (t == 1) ? Wk : Wv;
  floatx4 v = ((const floatx4*)src)[j];
  half4_t h = {(_Float16)v[0], (_Float16)v[1], (_Float16)v[2], (_Float16)v[3]};
  ((half4_t*)out)[i] = h;
}

// Row softmax over 1024 fp16 scores, fp32 math, fp16 result in place.
// One block per row; each thread owns 4 elements.
__global__ __launch_bounds__(256) void softmax_rows_h(_Float16* __restrict__ S) {
  long row = blockIdx.x;
  _Float16* Sr = S + row * 1024;
  int tid = threadIdx.x, lane = tid & 63, wid = tid >> 6;
  half4_t x = ((const half4_t*)Sr)[tid];
  float x0 = x[0], x1 = x[1], x2 = x[2], x3 = x[3];
  float mx = fmaxf(fmaxf(x0, x1), fmaxf(x2, x3));
#pragma unroll
  for (int off = 32; off > 0; off >>= 1) mx = fmaxf(mx, __shfl_xor(mx, off));
  __shared__ float redm[4];
  if (lane == 0) redm[wid] = mx;
  __syncthreads();
  mx = fmaxf(fmaxf(redm[0], redm[1]), fmaxf(redm[2], redm[3]));
  float e0 = __expf(x0 - mx), e1 = __expf(x1 - mx);
  float e2 = __expf(x2 - mx), e3 = __expf(x3 - mx);
  float s = e0 + e1 + e2 + e3;
#pragma unroll
  for (int off = 32; off > 0; off >>= 1) s += __shfl_xor(s, off);
  __shared__ float reds[4];
  if (lane == 0) reds[wid] = s;
  __syncthreads();
  s = reds[0] + reds[1] + reds[2] + reds[3];
  float inv = 1.0f / s;
  half4_t h = {(_Float16)(e0 * inv), (_Float16)(e1 * inv),
               (_Float16)(e2 * inv), (_Float16)(e3 * inv)};
  ((half4_t*)Sr)[tid] = h;
}

extern "C" void kernel_launch(void* const* d_in, const int* in_sizes, int n_in,
                              void* d_out, int out_size, void* d_ws,
                              size_t ws_size, hipStream_t stream) {
  (void)in_sizes; (void)n_in; (void)out_size; (void)ws_size;
  const float* meme  = (const float*)d_in[0];
  const float* text  = (const float*)d_in[1];
  const float* emoji = (const float*)d_in[2];
  const float* Wq = (const float*)d_in[3];
  const float* bq = (const float*)d_in[4];
  const float* Wk = (const float*)d_in[5];
  const float* bk = (const float*)d_in[6];
  const float* Wv = (const float*)d_in[7];
  const float* bv = (const float*)d_in[8];

  const long MB = 1024 * 1024;
  char* ws = (char*)d_ws;
  // [0,6) MB:    hWq/hWk/hWv fp16
  // [6,38) MB:   meme_h fp16  -> dead after Q GEMM  -> reused as S (fp16, 32MB)
  // [38,70) MB:  text_h fp16  -> dead after K GEMM  -> reused as Vt (fp16, 32MB)
  // [70,102) MB: emoji_h fp16 -> dead after Vt GEMM
  // [102,134):   Qh fp16   [134,166): Kh fp16       => total 166 MB
  _Float16* hWq = (_Float16*)ws;
  _Float16* mh  = (_Float16*)(ws + 6 * MB);
  _Float16* th  = (_Float16*)(ws + 38 * MB);
  _Float16* eh  = (_Float16*)(ws + 70 * MB);
  _Float16* Qh  = (_Float16*)(ws + 102 * MB);
  _Float16* Kh  = (_Float16*)(ws + 134 * MB);
  _Float16* S   = mh;  // aliases meme_h (dead by then)
  _Float16* Vt  = th;  // aliases text_h (dead by then)
  _Float16* hWk = hWq + MB;
  _Float16* hWv = hWk + MB;

  dim3 blk(256);
  convert_w<<<3072, blk, 0, stream>>>(Wq, Wk, Wv, hWq);
  convert_x<<<49152, blk, 0, stream>>>(meme, text, emoji, mh);

  // Q = meme @ Wq^T + bq  -> fp16 [16384,1024]
  gemm_bt<_Float16, 1><<<dim3(8, 128, 1), blk, 0, stream>>>(
      mh, 0, 1024, hWq, 0, 1024, Qh, 0, 1024, bq);
  // K = text @ Wk^T + bk
  gemm_bt<_Float16, 1><<<dim3(8, 128, 1), blk, 0, stream>>>(
      th, 0, 1024, hWk, 0, 1024, Kh, 0, 1024, bk);
  // Vt[a, b*L+l] = sum_h Wv[a,h]*emoji[b,l,h] + bv[a]   (V transposed)
  gemm_bt<_Float16, 2><<<dim3(128, 8, 1), blk, 0, stream>>>(
      hWv, 0, 1024, eh, 0, 1024, Vt, 0, 16384, bv);
  // S[b] = Q[b] @ K[b]^T  -> fp16
  gemm_bt<_Float16, 0><<<dim3(8, 8, 16), blk, 0, stream>>>(
      Qh, 1048576, 1024, Kh, 1048576, 1024, S, 1048576, 1024, nullptr);
  // softmax rows, fp16 in place
  softmax_rows_h<<<16384, blk, 0, stream>>>(S);
  // O[b] = P[b] @ V[b]  via Vt: C[q,a] = sum_k P[q,k] * Vt[a, b*1024+k]
  gemm_bt<float, 0><<<dim3(8, 8, 16), blk, 0, stream>>>(
      S, 1048576, 1024, Vt + 0, 1024, 16384, (float*)d_out,
      1048576, 1024, nullptr);
}

// Round 3
// 605.130 us; speedup vs baseline: 1.2904x; 1.1037x over previous
//
#include <hip/hip_runtime.h>

typedef _Float16 half8_t __attribute__((ext_vector_type(8)));
typedef _Float16 half4_t __attribute__((ext_vector_type(4)));
typedef float floatx4 __attribute__((ext_vector_type(4)));

// async global->LDS, 16B per lane. lds ptr must be wave-uniform; HW writes
// lane L's data at ldsbase + L*16.
__device__ inline void gload16(const void* g, void* l) {
  __builtin_amdgcn_global_load_lds(
      (const __attribute__((address_space(1))) unsigned int*)g,
      (__attribute__((address_space(3))) unsigned int*)l, 16, 0, 0);
}

// C[m,n] = sum_h A[m,h]*B[n,h] (+bias). fp16 operands, K-contiguous (BT form).
// BIAS: 0 none, 1 per-col bias[bz*biasStride+n], 2 per-row bias[m].
// MODE: 0 natural blockIdx.{x,y,z}
//       1 linear grid, proj swizzle: 8 n-blocks of one (z,m)-panel -> same XCD
//       2 linear grid, attn swizzle: 64 blocks of one batch z -> same XCD
constexpr int BM = 128, BN = 128, BK = 64, KDIM = 1024;

template <typename OT, int BIAS, int MODE>
__global__ __launch_bounds__(256) void gemm_bt(
    const _Float16* __restrict__ A, long As, int lda,
    const _Float16* __restrict__ B, long Bs, int ldb,
    OT* __restrict__ C, long Cs, int ldc,
    const float* __restrict__ bias, int biasStride) {
  // BK=64: 8 16B-chunks per row; 128 rows -> 16 KB per operand tile
  __shared__ char smem[2 * 8 * 128 * 16];
  char* sA = smem;
  char* sB = smem + 8 * 128 * 16;

  int bx, by, bz;
  if constexpr (MODE == 0) {
    bx = blockIdx.x; by = blockIdx.y; bz = blockIdx.z;
  } else if constexpr (MODE == 1) {
    // id = c + 8*(h*8 + j), panel g = h*8+c, XCD = id%8 = c (assumed RR)
    int id = blockIdx.x;
    int c = id & 7, r = id >> 3;
    int j = r & 7, h = r >> 3;
    int g = h * 8 + c;          // panel in [0, 128*NZ)
    bx = j; by = g & 127; bz = g >> 7;
  } else {
    int id = blockIdx.x;        // 1024 = 8x8x16
    int c = id & 7, r = id >> 3;
    int j = r & 63, h = r >> 6;
    bx = j & 7; by = j >> 3; bz = h * 8 + c;
  }

  const int tid = threadIdx.x;
  const int lane = tid & 63;
  const int wid = tid >> 6;
  const int wm = wid >> 1, wn = wid & 1;
  const int quad = lane >> 4;
  const int mrow = lane & 15;
  const long m0 = (long)by * BM;
  const long n0 = (long)bx * BN;
  A += (long)bz * As;
  B += (long)bz * Bs;
  C += (long)bz * Cs;

  floatx4 acc[4][4] = {};

  for (int k0 = 0; k0 < KDIM; k0 += BK) {
    // stage A: 8 chunks/row * 128 rows = 1024 chunks; 4 gload16 per wave
#pragma unroll
    for (int i = 0; i < 4; ++i) {
      int lin = (wid * 4 + i) * 64 + lane;
      int m = lin & 127;
      int kb = lin >> 7;
      gload16(A + (m0 + m) * (long)lda + k0 + kb * 8,
              sA + (long)((wid * 4 + i) * 64) * 16);
    }
#pragma unroll
    for (int i = 0; i < 4; ++i) {
      int lin = (wid * 4 + i) * 64 + lane;
      int m = lin & 127;
      int kb = lin >> 7;
      gload16(B + (n0 + m) * (long)ldb + k0 + kb * 8,
              sB + (long)((wid * 4 + i) * 64) * 16);
    }
    __syncthreads();  // drains vmcnt before s_barrier

    // two K=32 sub-steps per staged tile
#pragma unroll
    for (int kk = 0; kk < 2; ++kk) {
      half8_t af[4], bf[4];
#pragma unroll
      for (int i = 0; i < 4; ++i)
        af[i] = *(const half8_t*)(
            sA + (((kk * 4 + quad) * 128 + wm * 64 + i * 16 + mrow) << 4));
#pragma unroll
      for (int j = 0; j < 4; ++j)
        bf[j] = *(const half8_t*)(
            sB + (((kk * 4 + quad) * 128 + wn * 64 + j * 16 + mrow) << 4));
#pragma unroll
      for (int i = 0; i < 4; ++i)
#pragma unroll
        for (int j = 0; j < 4; ++j)
          acc[i][j] = __builtin_amdgcn_mfma_f32_16x16x32_f16(
              af[i], bf[j], acc[i][j], 0, 0, 0);
    }
    __syncthreads();
  }

  // epilogue: C/D layout col = lane&15, row = quad*4 + r
#pragma unroll
  for (int i = 0; i < 4; ++i) {
    int rbase = wm * 64 + i * 16 + quad * 4;
#pragma unroll
    for (int j = 0; j < 4; ++j) {
      int cc = (int)n0 + wn * 64 + j * 16 + mrow;
#pragma unroll
      for (int r = 0; r < 4; ++r) {
        long row = m0 + rbase + r;
        float v = acc[i][j][r];
        if constexpr (BIAS == 1) v += bias[bz * biasStride + cc];
        if constexpr (BIAS == 2) v += bias[(int)row];
        C[row * (long)ldc + cc] = (OT)v;
      }
    }
  }
}

// fp32 -> fp16, one float4 chunk per thread, 3 tensors of 16M floats each.
__global__ __launch_bounds__(256) void convert_x(const float* __restrict__ x0,
                                                 const float* __restrict__ x1,
                                                 const float* __restrict__ x2,
                                                 _Float16* __restrict__ out) {
  int i = blockIdx.x * 256 + threadIdx.x;  // 12582912 chunks total
  int t = i >> 22;                         // 4194304 chunks per tensor
  int j = i & 4194303;
  const float* src = (t == 0) ? x0 : (t == 1) ? x1 : x2;
  floatx4 v = ((const floatx4*)src)[j];
  half4_t h = {(_Float16)v[0], (_Float16)v[1], (_Float16)v[2], (_Float16)v[3]};
  ((half4_t*)out)[i] = h;
}

__global__ __launch_bounds__(256) void convert_w(const float* __restrict__ Wq,
                                                 const float* __restrict__ Wk,
                                                 const float* __restrict__ Wv,
                                                 _Float16* __restrict__ out) {
  int i = blockIdx.x * 256 + threadIdx.x;  // 786432 chunks total
  int t = i >> 18;                         // 262144 chunks per tensor
  int j = i & 262143;
  const float* src = (t == 0) ? Wq : (t == 1) ? Wk : Wv;
  floatx4 v = ((const floatx4*)src)[j];
  half4_t h = {(_Float16)v[0], (_Float16)v[1], (_Float16)v[2], (_Float16)v[3]};
  ((half4_t*)out)[i] = h;
}

// pack bq|bk|bv into one contiguous [3*1024] float array
__global__ __launch_bounds__(256) void pack_bias(const float* __restrict__ bq,
                                                 const float* __restrict__ bk,
                                                 const float* __restrict__ bv,
                                                 float* __restrict__ out) {
  int b = blockIdx.x;
  const float* src = (b == 0) ? bq : (b == 1) ? bk : bv;
  ((floatx4*)out)[b * 256 + threadIdx.x] =
      ((const floatx4*)src)[threadIdx.x];
}

// Row softmax over 1024 fp16 scores, fp32 math, fp16 result in place.
__global__ __launch_bounds__(256) void softmax_rows_h(_Float16* __restrict__ S) {
  long row = blockIdx.x;
  _Float16* Sr = S + row * 1024;
  int tid = threadIdx.x, lane = tid & 63, wid = tid >> 6;
  half4_t x = ((const half4_t*)Sr)[tid];
  float x0 = x[0], x1 = x[1], x2 = x[2], x3 = x[3];
  float mx = fmaxf(fmaxf(x0, x1), fmaxf(x2, x3));
#pragma unroll
  for (int off = 32; off > 0; off >>= 1) mx = fmaxf(mx, __shfl_xor(mx, off));
  __shared__ float redm[4];
  if (lane == 0) redm[wid] = mx;
  __syncthreads();
  mx = fmaxf(fmaxf(redm[0], redm[1]), fmaxf(redm[2], redm[3]));
  float e0 = __expf(x0 - mx), e1 = __expf(x1 - mx);
  float e2 = __expf(x2 - mx), e3 = __expf(x3 - mx);
  float s = e0 + e1 + e2 + e3;
#pragma unroll
  for (int off = 32; off > 0; off >>= 1) s += __shfl_xor(s, off);
  __shared__ float reds[4];
  if (lane == 0) reds[wid] = s;
  __syncthreads();
  s = reds[0] + reds[1] + reds[2] + reds[3];
  float inv = 1.0f / s;
  half4_t h = {(_Float16)(e0 * inv), (_Float16)(e1 * inv),
               (_Float16)(e2 * inv), (_Float16)(e3 * inv)};
  ((half4_t*)Sr)[tid] = h;
}

extern "C" void kernel_launch(void* const* d_in, const int* in_sizes, int n_in,
                              void* d_out, int out_size, void* d_ws,
                              size_t ws_size, hipStream_t stream) {
  (void)in_sizes; (void)n_in; (void)out_size; (void)ws_size;
  const float* meme  = (const float*)d_in[0];
  const float* text  = (const float*)d_in[1];
  const float* emoji = (const float*)d_in[2];
  const float* Wq = (const float*)d_in[3];
  const float* bq = (const float*)d_in[4];
  const float* Wk = (const float*)d_in[5];
  const float* bk = (const float*)d_in[6];
  const float* Wv = (const float*)d_in[7];
  const float* bv = (const float*)d_in[8];

  const long MB = 1024 * 1024;
  char* ws = (char*)d_ws;
  // [0,6) MB:    hWq/hWk/hWv fp16 (contiguous, stride 1M halves)
  // [6, 6.0125): packed bias 3*1024 fp32 (12 KB) -> round region to 7 MB
  // [7,39) MB:   meme_h  -> dead after QK GEMM -> reused as S (fp16, 32MB)
  // [39,71) MB:  text_h  -> dead after QK GEMM -> reused as Vt (fp16, 32MB)
  // [71,103) MB: emoji_h -> dead after Vt GEMM
  // [103,135):   Qh fp16   [135,167): Kh fp16   => total 167 MB
  _Float16* hWq = (_Float16*)ws;
  float* pbias  = (float*)(ws + 6 * MB);
  _Float16* mh  = (_Float16*)(ws + 7 * MB);
  _Float16* th  = (_Float16*)(ws + 39 * MB);
  _Float16* eh  = (_Float16*)(ws + 71 * MB);
  _Float16* Qh  = (_Float16*)(ws + 103 * MB);
  _Float16* Kh  = (_Float16*)(ws + 135 * MB);
  _Float16* S   = mh;  // aliases meme_h (dead by then)
  _Float16* Vt  = th;  // aliases text_h (dead by then)
  _Float16* hWv = hWq + 2 * MB;

  dim3 blk(256);
  convert_w<<<3072, blk, 0, stream>>>(Wq, Wk, Wv, hWq);
  pack_bias<<<3, blk, 0, stream>>>(bq, bk, bv, pbias);
  convert_x<<<49152, blk, 0, stream>>>(meme, text, emoji, mh);

  // Q,K projections batched (z=2): A stride mh->th = 16M halves,
  // B stride hWq->hWk = 1M halves, C stride Qh->Kh = 16M halves.
  gemm_bt<_Float16, 1, 1><<<dim3(2048), blk, 0, stream>>>(
      mh, 16777216, 1024, hWq, 1048576, 1024, Qh, 16777216, 1024, pbias, 1024);
  // Vt[a, b*L+l] = sum_h Wv[a,h]*emoji[b,l,h] + bv[a]   (V transposed)
  gemm_bt<_Float16, 2, 0><<<dim3(128, 8, 1), blk, 0, stream>>>(
      hWv, 0, 1024, eh, 0, 1024, Vt, 0, 16384, pbias + 2048, 0);
  // S[b] = Q[b] @ K[b]^T  -> fp16
  gemm_bt<_Float16, 0, 2><<<dim3(1024), blk, 0, stream>>>(
      Qh, 1048576, 1024, Kh, 1048576, 1024, S, 1048576, 1024, nullptr, 0);
  // softmax rows, fp16 in place
  softmax_rows_h<<<16384, blk, 0, stream>>>(S);
  // O[b] = P[b] @ V[b]  via Vt: C[q,a] = sum_k P[q,k] * Vt[a, b*1024+k]
  gemm_bt<float, 0, 2><<<dim3(1024), blk, 0, stream>>>(
      S, 1048576, 1024, Vt, 1024, 16384, (float*)d_out, 1048576, 1024,
      nullptr, 0);
}